// Round 9
// baseline (220.878 us; speedup 1.0000x reference)
//
#include <hip/hip_runtime.h>

// B=32, N=1024, D=256. out = softmax((x Wq^T + bq)(x Wk^T + bk)^T) (x Wv^T + bv)
// fp16 MFMA, fp32 accumulate. R9: attn = 32 q-rows/wave (2 A-sets: every K/V
// B-fragment feeds 2 MFMAs -> DS traffic halves), 256 blocks (1/CU), full dbuf
// K+V, per-wave S region, ONE barrier/tile. proj = W e-quarter staged once
// (zero loop barriers), fp16 packed-A pre-pass.
#define NN 1024
#define DD 256

typedef __attribute__((ext_vector_type(8))) _Float16 f16x8;  // 8 fp16 = 4 VGPRs
typedef __attribute__((ext_vector_type(4))) float f32x4;

union H8 { f16x8 v; _Float16 s[8]; };

__device__ __forceinline__ void g2lds16(const void* g, void* l) {
  __builtin_amdgcn_global_load_lds(
      (const __attribute__((address_space(1))) void*)g,
      (__attribute__((address_space(3))) void*)l, 16, 0, 0);
}

// ---------------- kernel 0: pack traj fp32 -> fp16 A-fragment-major ------------------
// pa chunk c = (g*8+kk)*64+lane ; data = traj[m=g*16+c16][d=kk*32+qd*8..+7]
__global__ void apack_kernel(const float* __restrict__ traj, _Float16* __restrict__ pa) {
  int c = blockIdx.x * 256 + threadIdx.x;        // < 1048576
  int lane = c & 63;
  int kk = (c >> 6) & 7;
  int g = c >> 9;
  const float* src = traj + (size_t)(g * 16 + (lane & 15)) * 256 + kk * 32 + (lane >> 4) * 8;
  H8 xx;
  for (int j = 0; j < 8; ++j) xx.s[j] = (_Float16)src[j];
  *(f16x8*)(pa + (size_t)c * 8) = xx.v;
}

// ---------------- kernel 1: pack W fp32 -> fp16 fragment-major (32-col tiles) -------
// chunk c = ((et*8+kk)*2+nt)*64+lane ; data = W[e=et*32+nt*16+c16][d=kk*32+qd*8..+7]
__global__ void wconv_kernel(const float* __restrict__ Wq, const float* __restrict__ Wk,
                             const float* __restrict__ Wv, _Float16* __restrict__ pw) {
  int c = blockIdx.x * 256 + threadIdx.x;        // < 24576
  int lane = c & 63;
  int nt = (c >> 6) & 1;
  int kk = (c >> 7) & 7;
  int et = c >> 10;                              // 0..23
  int e = et * 32 + nt * 16 + (lane & 15);
  int d = kk * 32 + (lane >> 4) * 8;
  const float* W = (e < 256) ? Wq : (e < 512 ? Wk : Wv);
  const float* src = W + (e & 255) * 256 + d;
  H8 xx;
  for (int j = 0; j < 8; ++j) xx.s[j] = (_Float16)src[j];
  *(f16x8*)(pw + (size_t)c * 8) = xx.v;
}

// ---------------- kernel 2: QKV projection -------------------------------------------
// grid 1024 = 256 m-tiles(128 rows) x 4 e-quarters(192 cols). 4 waves x 32 rows
// (2 A-sets). W quarter (96KB) staged ONCE; main loop barrier-free.
__global__ __launch_bounds__(256, 1) void proj_kernel(
    const _Float16* __restrict__ pa,
    const float* __restrict__ bq, const float* __restrict__ bk, const float* __restrict__ bv,
    const _Float16* __restrict__ pw,
    _Float16* __restrict__ pq, _Float16* __restrict__ pk, _Float16* __restrict__ pv)
{
  __shared__ alignas(16) _Float16 Wl[49152];     // 96 KB: 6 x 32-col W tiles
  __shared__ alignas(16) _Float16 Cs[4][1280];   // per-wave 2.5 KB staging

  const int t = threadIdx.x;
  const int lane = t & 63, wave = t >> 6;
  const int col16 = lane & 15, quad = lane >> 4;
  const int mt = blockIdx.x >> 2, eq = blockIdx.x & 3;
  const int mbase = mt * 128;
  const int bb = mbase >> 10;

  // stage W quarter (tiles eq*6 .. eq*6+5), linear 16B/thread
  {
    const _Float16* ws = pw + (size_t)eq * 6 * 8192;
    for (int i = 0; i < 24; ++i)
      g2lds16(ws + (size_t)(i * 256 + t) * 8, Wl + (i * 256 + t) * 8);
  }

  // A fragments (2 sets of 16 rows) from packed fp16
  f16x8 aq[2][8];
  for (int s = 0; s < 2; ++s) {
    int g = (mbase >> 4) + wave * 2 + s;
    for (int kk = 0; kk < 8; ++kk)
      aq[s][kk] = *(const f16x8*)(pa + (size_t)((g * 8 + kk) * 64 + lane) * 8);
  }

  __syncthreads();                     // W staged; only barrier in the kernel
  const f32x4 zero = {0.f, 0.f, 0.f, 0.f};

  for (int ei = 0; ei < 6; ++ei) {
    f32x4 acc[2][2];
    acc[0][0] = zero; acc[0][1] = zero; acc[1][0] = zero; acc[1][1] = zero;
    for (int kk = 0; kk < 8; ++kk)
      for (int nt = 0; nt < 2; ++nt) {
        f16x8 bw = *(const f16x8*)&Wl[((ei * 16 + kk * 2 + nt) * 64 + lane) * 8];
        acc[0][nt] = __builtin_amdgcn_mfma_f32_16x16x32_f16(aq[0][kk], bw, acc[0][nt], 0, 0, 0);
        acc[1][nt] = __builtin_amdgcn_mfma_f32_16x16x32_f16(aq[1][kk], bw, acc[1][nt], 0, 0, 0);
      }

    int e0 = eq * 192 + ei * 32;
    int sel = e0 >> 8;                 // 0=q 1=k 2=v
    const float* bias = (sel == 0) ? bq : (sel == 1 ? bk : bv);
    for (int nt = 0; nt < 2; ++nt) {
      float bvl = bias[(e0 & 255) + nt * 16 + col16];
      for (int s = 0; s < 2; ++s) {
        acc[s][nt][0] += bvl; acc[s][nt][1] += bvl;
        acc[s][nt][2] += bvl; acc[s][nt][3] += bvl;
      }
    }

    _Float16* cs = Cs[wave];           // wave-private: in-order DS pipe, no barriers
    if (sel < 2) {
      for (int s = 0; s < 2; ++s)
        for (int nt = 0; nt < 2; ++nt)
          for (int r = 0; r < 4; ++r)
            cs[(s * 16 + quad * 4 + r) * 40 + nt * 16 + col16] = (_Float16)acc[s][nt][r];
      if (sel == 0) {
        int kkq = e0 >> 5;
        for (int s = 0; s < 2; ++s) {
          f16x8 val = *(const f16x8*)&cs[(s * 16 + col16) * 40 + quad * 8];
          int g = (mbase >> 4) + wave * 2 + s;
          *(f16x8*)(pq + (size_t)((g * 8 + kkq) * 64 + lane) * 8) = val;
        }
      } else {
        int kkg = (e0 - 256) >> 5;
        for (int s = 0; s < 2; ++s) {
          f16x8 val = *(const f16x8*)&cs[(s * 16 + col16) * 40 + quad * 8];
          int kgg = ((mbase & 1023) >> 4) + wave * 2 + s;
          *(f16x8*)(pk + (size_t)(((bb * 64 + kgg) * 8 + kkg) * 64 + lane) * 8) = val;
        }
      }
    } else {
      // transposed staging: row = e_local (stride 40), col = m_local 0..31
      for (int s = 0; s < 2; ++s)
        for (int nt = 0; nt < 2; ++nt)
          for (int r = 0; r < 4; ++r)
            cs[(nt * 16 + col16) * 40 + s * 16 + quad * 4 + r] = (_Float16)acc[s][nt][r];
      int kt32 = ((mbase & 1023) >> 5) + wave;   // wave's 32 rows = one 32-key group
      for (int dtl = 0; dtl < 2; ++dtl) {
        f16x8 val = *(const f16x8*)&cs[(dtl * 16 + col16) * 40 + quad * 8];
        int dtg = ((e0 - 512) >> 4) + dtl;
        *(f16x8*)(pv + (size_t)(((bb * 32 + kt32) * 16 + dtg) * 64 + lane) * 8) = val;
      }
    }
  }
}

// ---------------- kernel 3: flash attention ------------------------------------------
// grid (32 b, 8 qt) = 256 blocks (1/CU); 4 waves x 32 q-rows (2 A-sets). Full
// dbuf K+V (32-key tiles), per-wave S region -> ONE barrier per tile.
__global__ __launch_bounds__(256, 1) void attn_kernel(
    const _Float16* __restrict__ pq, const _Float16* __restrict__ pk,
    const _Float16* __restrict__ pv, float* __restrict__ out)
{
  __shared__ alignas(16) _Float16 Ks[2][8192];   // 2 x 16 KB (32 keys x 256 d)
  __shared__ alignas(16) _Float16 Vs[2][8192];   // 2 x 16 KB
  __shared__ alignas(16) float Sp[4][1056];      // per-wave 32 rows x stride 33

  const int t = threadIdx.x;
  const int lane = t & 63, wave = t >> 6;
  const int col16 = lane & 15, quad = lane >> 4;
  const int b = blockIdx.x, qt = blockIdx.y;     // bid%8 = b%8 -> per-batch XCD
  const int qrow0 = b * NN + qt * 128;

  // Q fragments (2 sets of 16 rows) from packed global
  f16x8 aq[2][8];
  for (int s = 0; s < 2; ++s) {
    int g = b * 64 + qt * 8 + wave * 2 + s;
    for (int kk = 0; kk < 8; ++kk)
      aq[s][kk] = *(const f16x8*)(pq + (size_t)((g * 8 + kk) * 64 + lane) * 8);
  }

  float m_i[2] = {-3.0e38f, -3.0e38f}, l_i[2] = {0.f, 0.f};
  f32x4 O[2][16];
  const f32x4 zero = {0.f, 0.f, 0.f, 0.f};
  for (int s = 0; s < 2; ++s)
    for (int dt = 0; dt < 16; ++dt) O[s][dt] = zero;

  const _Float16* kbb = pk + (size_t)b * 64 * 8 * 64 * 8;
  const _Float16* vbb = pv + (size_t)b * 32 * 16 * 64 * 8;

  // prologue: stage tile 0
  for (int i = 0; i < 4; ++i)
    g2lds16(kbb + (size_t)(i * 256 + t) * 8, Ks[0] + (i * 256 + t) * 8);
  for (int i = 0; i < 4; ++i)
    g2lds16(vbb + (size_t)(i * 256 + t) * 8, Vs[0] + (i * 256 + t) * 8);

  for (int kt = 0; kt < 32; ++kt) {
    __syncthreads();                   // tile kt landed; buf (kt+1)&1 reads retired
    if (kt < 31) {                     // prefetch tile kt+1 (flies ~1 full tile)
      const _Float16* kg = kbb + (size_t)(kt + 1) * 8192;
      const _Float16* vg = vbb + (size_t)(kt + 1) * 8192;
      _Float16* kd = Ks[(kt + 1) & 1];
      _Float16* vd = Vs[(kt + 1) & 1];
      for (int i = 0; i < 4; ++i)
        g2lds16(kg + (size_t)(i * 256 + t) * 8, kd + (i * 256 + t) * 8);
      for (int i = 0; i < 4; ++i)
        g2lds16(vg + (size_t)(i * 256 + t) * 8, vd + (i * 256 + t) * 8);
    }

    // S = Q K^T (32 keys x 32 rows); each B-frag feeds both A-sets
    const _Float16* ks = Ks[kt & 1];
    f32x4 S[2][2];
    S[0][0] = zero; S[0][1] = zero; S[1][0] = zero; S[1][1] = zero;
    for (int kk = 0; kk < 8; ++kk) {
      f16x8 bk0 = *(const f16x8*)&ks[((0 * 8 + kk) * 64 + lane) * 8];
      f16x8 bk1 = *(const f16x8*)&ks[((1 * 8 + kk) * 64 + lane) * 8];
      S[0][0] = __builtin_amdgcn_mfma_f32_16x16x32_f16(aq[0][kk], bk0, S[0][0], 0, 0, 0);
      S[0][1] = __builtin_amdgcn_mfma_f32_16x16x32_f16(aq[0][kk], bk1, S[0][1], 0, 0, 0);
      S[1][0] = __builtin_amdgcn_mfma_f32_16x16x32_f16(aq[1][kk], bk0, S[1][0], 0, 0, 0);
      S[1][1] = __builtin_amdgcn_mfma_f32_16x16x32_f16(aq[1][kk], bk1, S[1][1], 0, 0, 0);
    }

    // per-wave S round trip (C layout -> A layout), wave-private: no barrier
    float* sp = Sp[wave];
    for (int s = 0; s < 2; ++s)
      for (int nt = 0; nt < 2; ++nt)
        for (int r = 0; r < 4; ++r)
          sp[(s * 16 + quad * 4 + r) * 33 + nt * 16 + col16] = S[s][nt][r];

    f16x8 ap[2];
    float alpha[2];
    for (int s = 0; s < 2; ++s) {
      float sv[8];
      *(f32x4*)&sv[0] = *(const f32x4*)&sp[(s * 16 + col16) * 33 + quad * 8];
      *(f32x4*)&sv[4] = *(const f32x4*)&sp[(s * 16 + col16) * 33 + quad * 8 + 4];
      float vmax = sv[0];
      for (int j = 1; j < 8; ++j) vmax = fmaxf(vmax, sv[j]);
      vmax = fmaxf(vmax, __shfl_xor(vmax, 16));
      vmax = fmaxf(vmax, __shfl_xor(vmax, 32));
      float nm = fmaxf(m_i[s], vmax);
      alpha[s] = __expf(m_i[s] - nm);
      float rs = 0.f;
      H8 px;
      for (int j = 0; j < 8; ++j) {
        float pj = __expf(sv[j] - nm);
        rs += pj;
        px.s[j] = (_Float16)pj;
      }
      rs += __shfl_xor(rs, 16);
      rs += __shfl_xor(rs, 32);
      l_i[s] = l_i[s] * alpha[s] + rs;
      m_i[s] = nm;
      ap[s] = px.v;
    }

    // O-rescale (exact skip when no row's max moved)
    if (__ballot(fminf(alpha[0], alpha[1]) < 1.0f)) {
      for (int s = 0; s < 2; ++s) {
        float a4[4];
        for (int r = 0; r < 4; ++r) a4[r] = __shfl(alpha[s], quad * 4 + r);
        for (int dt = 0; dt < 16; ++dt)
          for (int r = 0; r < 4; ++r) O[s][dt][r] *= a4[r];
      }
    }

    // O += P V; each V fragment feeds both A-sets
    const _Float16* vs = Vs[kt & 1];
    for (int dt = 0; dt < 16; ++dt) {
      f16x8 bv_ = *(const f16x8*)&vs[(dt * 64 + lane) * 8];
      O[0][dt] = __builtin_amdgcn_mfma_f32_16x16x32_f16(ap[0], bv_, O[0][dt], 0, 0, 0);
      O[1][dt] = __builtin_amdgcn_mfma_f32_16x16x32_f16(ap[1], bv_, O[1][dt], 0, 0, 0);
    }
  }

  // epilogue: O /= l, fp32 store
  for (int s = 0; s < 2; ++s) {
    float linv[4];
    for (int r = 0; r < 4; ++r) linv[r] = 1.0f / __shfl(l_i[s], quad * 4 + r);
    for (int r = 0; r < 4; ++r) {
      float* orow = out + (size_t)(qrow0 + wave * 32 + s * 16 + quad * 4 + r) * DD;
      for (int dt = 0; dt < 16; ++dt)
        orow[dt * 16 + col16] = O[s][dt][r] * linv[r];
    }
  }
}

// ---------------- launch -------------------------------------------------------------
extern "C" void kernel_launch(void* const* d_in, const int* in_sizes, int n_in,
                              void* d_out, int out_size, void* d_ws, size_t ws_size,
                              hipStream_t stream) {
  const float* traj = (const float*)d_in[0];
  const float* Wq   = (const float*)d_in[1];
  const float* bq   = (const float*)d_in[2];
  const float* Wk   = (const float*)d_in[3];
  const float* bk   = (const float*)d_in[4];
  const float* Wv   = (const float*)d_in[5];
  const float* bv   = (const float*)d_in[6];

  // workspace (fp16): pq 16MB | pk 16MB | pv 16MB | pa 16MB | pw 0.4MB (all packed)
  _Float16* pq = (_Float16*)d_ws;
  _Float16* pk = pq + (size_t)32768 * 256;
  _Float16* pv = pk + (size_t)32768 * 256;
  _Float16* pa = pv + (size_t)32768 * 256;
  _Float16* pw = pa + (size_t)32768 * 256;   // ~64.4 MB total

  apack_kernel<<<4096, 256, 0, stream>>>(traj, pa);
  wconv_kernel<<<96, 256, 0, stream>>>(Wq, Wk, Wv, pw);
  proj_kernel<<<1024, 256, 0, stream>>>(pa, bq, bk, bv, pw, pq, pk, pv);
  attn_kernel<<<dim3(32, 8), 256, 0, stream>>>(pq, pk, pv, (float*)d_out);
}